// Round 7
// baseline (218.665 us; speedup 1.0000x reference)
//
#include <hip/hip_runtime.h>

#define B_ROWS 4096
#define N_CLUST 1024
#define KDIM 4096
#define NKT 32          // source k-tiles of 128 halfs
#define NSTEP 32        // BK=32 steps per block (split-K x4: 1024 = 32 x 32)

#define EMA_OLD 0.01f
#define EMA_NEW 0.99f
#define MARGIN 2.0f     // screen error: ~0.27 f16 + 0.125 i16 quant << 2.0
#define PSCALE 16.0f    // i16 partial quantization scale
#define PLANE ((size_t)B_ROWS * N_CLUST)

typedef unsigned short ushortT;
typedef _Float16 half8 __attribute__((ext_vector_type(8)));
typedef short short8v __attribute__((ext_vector_type(8)));
typedef float f32x16 __attribute__((ext_vector_type(16)));

// ---------------- workspace layout (bytes) ----------------
#define WS_WINNER_OFF 0                  // i32[1024], init by convert_sumsq
#define WS_YY_OFF     20480              // f32[4096]
#define WS_MM_OFF     36864              // f32[1024]
#define WS_P_OFF      65536              // i16[4][4096][1024] = 4 x 8 MiB
#define WS_YHI_OFF    (WS_P_OFF + 33554432)      // 33.6 MB
#define WS_MHI_OFF    (WS_YHI_OFF + 33554432)    // 8.4 MB
#define WS_END        (WS_MHI_OFF + 8388608)     // ~75 MB

// ---------------- fused f16-hi convert + row sum-of-squares ----------------
// Tiled layout: block (rb, kt) of 64 rows x 128 halfs contiguous (16 KB).
// Within a row (16 chunks of 16B), logical chunk c stored at p = c ^ (r&15).
// m-branch blocks also init winner[row] = -1 (replaces the memset node).
__global__ __launch_bounds__(256) void convert_sumsq(
    const float* __restrict__ ysrc, const float* __restrict__ msrc,
    ushortT* __restrict__ yhi, ushortT* __restrict__ mhi,
    float* __restrict__ yy, float* __restrict__ mm,
    int* __restrict__ winner) {
    const int blk = blockIdx.x;
    const float* src;
    ushortT* hi;
    float* out;
    int row;
    if (blk < B_ROWS) {
        src = ysrc; hi = yhi; out = yy + blk; row = blk;
    } else {
        row = blk - B_ROWS;
        src = msrc; hi = mhi; out = mm + row;
        if (threadIdx.x == 0) winner[row] = -1;   // fused memset
    }
    const int r = row & 63, rb = row >> 6;
    const int t = threadIdx.x;
    float s = 0.f;
#pragma unroll
    for (int h = 0; h < 2; ++h) {
        int ci = h * 256 + t;        // physical chunk in row [0,512)
        int kt = ci >> 4, p = ci & 15;
        int c = p ^ (r & 15);
        const float* sp = src + ((size_t)row << 12) + kt * 128 + c * 8;
        float4 v0 = *(const float4*)sp;
        float4 v1 = *(const float4*)(sp + 4);
        float vv[8] = {v0.x, v0.y, v0.z, v0.w, v1.x, v1.y, v1.z, v1.w};
        half8 hv;
#pragma unroll
        for (int i = 0; i < 8; ++i) {
            hv[i] = (_Float16)vv[i];
            s += vv[i] * vv[i];
        }
        size_t off = (((size_t)rb * NKT + kt) * 64 + r) * 128 + p * 8;
        *(half8*)(hi + off) = hv;
    }
    for (int off = 32; off > 0; off >>= 1) s += __shfl_down(s, off, 64);
    __shared__ float red[4];
    if ((t & 63) == 0) red[t >> 6] = s;
    __syncthreads();
    if (t == 0) out[0] = red[0] + red[1] + red[2] + red[3];
}

// ---------------- screen GEMM: partials of -2*Yhi@Mhi^T ------------------
__device__ __forceinline__ void gload_lds16(const void* g, void* l) {
    __builtin_amdgcn_global_load_lds(
        (const __attribute__((address_space(1))) unsigned int*)g,
        (__attribute__((address_space(3))) unsigned int*)l, 16, 0, 0);
}

// v8 LDS layout (BK=32, conflict-free): 4-row groups of 256 B.
// phys(r, c) : group q = r>>2, slot = (((r&3)<<2)|c) ^ (q&15);
// half-addr = q*128 + slot*8. A wave's 32-lane column read (r = base..base+31,
// c fixed) spans 8 groups x 4 slots covering all 16 slot positions exactly
// twice -> 2-way = free (same criterion as v5's layout, measured 0).
__device__ __forceinline__ half8 ldfrag32(const ushortT* s, int r, int c) {
    int q = r >> 2;
    int sl = ((((r & 3) << 2) | c) ^ (q & 15));
    return *(const half8*)(s + q * 128 + sl * 8);
}

// v8: BK=32 double-buffer -> BOTH levers at once: 2 bufs x (8KB A + 8KB B)
// = 32 KB LDS -> 4 blocks/CU (v5's proven TLP) AND counted-vmcnt pipeline
// (v7's no-drain). Split-K x4, grid 1024 = 32 bx x 8 by (XCD-pinned) x 4 kh.
// Per step: issue next step's 4 gloads/wave, s_waitcnt vmcnt(4) (current
// step only - prefetch stays in flight across the barrier), barrier,
// 8 ds_read_b128 + 8 MFMA (setprio-wrapped), barrier.
// Accumulation order identical to v5 -> i16 partials bit-identical.
__global__ __launch_bounds__(256, 4) void screen_gemm(
    const ushortT* __restrict__ Ah, const ushortT* __restrict__ Bh,
    short* __restrict__ pws) {
    __shared__ __align__(16) ushortT sA[2][128 * 32];   // 2 x 8 KB
    __shared__ __align__(16) ushortT sB[2][128 * 32];   // 2 x 8 KB

    const int t = threadIdx.x, w = t >> 6, l = t & 63;
    const int by = blockIdx.x & 7;            // col panel -> XCD pinned
    const int kh = (blockIdx.x >> 3) & 3;     // K quarter
    const int bx = blockIdx.x >> 5;           // row tile 0..31
    const int row0 = bx * 128, col0 = by * 128;
    const int wr = (w >> 1) * 64, wc = (w & 1) * 64;   // wave 64x64 tile
    const int m0 = l & 31, hsel = l >> 5;

    // Per-lane source offsets for this wave's 2 staged chunks (same formula
    // for A and B). Chunk g covers LDS bytes [g*1024,(g+1)*1024) = groups
    // 4g..4g+3. Lane L -> (q = 4g + (L>>4), slot = L&15); decode
    // u = slot^(q&15), r_loc = 4q + (u>>2), c_loc = u&3; source row
    // R = r_loc&63 (tile = g>>2), phys chunk p = ((ks2<<2)|c_loc) ^ (R&15)
    // -> byte = R*256 + p*16; ks2 enters as pure XOR of byte bit 6.
    int lane01[2];
#pragma unroll
    for (int j = 0; j < 2; ++j) {
        int g = w * 2 + j;
        int q = 4 * g + (l >> 4);
        int u = (l & 15) ^ (q & 15);
        int rl = 4 * q + (u >> 2);
        int R = rl & 63;
        int p0 = (R & 12) | ((u & 3) ^ (R & 3));
        lane01[j] = R * 256 + (p0 << 4);
    }

    f32x16 acc[2][2];
#pragma unroll
    for (int i = 0; i < 2; ++i)
#pragma unroll
        for (int j = 0; j < 2; ++j)
#pragma unroll
            for (int r = 0; r < 16; ++r) acc[i][j][r] = 0.f;

    const int ra0 = wr + m0, ra1 = wr + 32 + m0;
    const int rb0 = wc + m0, rb1 = wc + 32 + m0;

#define STAGE(buf, step)                                                      \
    {                                                                         \
        const int kt_ = kh * 8 + ((step) >> 2);                               \
        const int x2_ = ((step) & 3) << 6;                                    \
        _Pragma("unroll")                                                     \
        for (int j = 0; j < 2; ++j) {                                         \
            const int g = w * 2 + j;                                          \
            const size_t tbA =                                                \
                ((size_t)((2 * bx + (g >> 2)) * NKT + kt_) << 14);            \
            gload_lds16((const char*)Ah + tbA + (lane01[j] ^ x2_),            \
                        (char*)&sA[buf][0] + g * 1024);                       \
            const size_t tbB =                                                \
                ((size_t)((2 * by + (g >> 2)) * NKT + kt_) << 14);            \
            gload_lds16((const char*)Bh + tbB + (lane01[j] ^ x2_),            \
                        (char*)&sB[buf][0] + g * 1024);                       \
        }                                                                     \
    }

    STAGE(0, 0);                       // prologue: 4 loads in flight

#pragma unroll 4
    for (int i = 0; i < NSTEP; ++i) {
        const int buf = i & 1;
        if (i + 1 < NSTEP) {
            STAGE(buf ^ 1, i + 1);                        // 8 in flight
            asm volatile("s_waitcnt vmcnt(4)" ::: "memory");  // drain step i only
        } else {
            asm volatile("s_waitcnt vmcnt(0)" ::: "memory");
        }
        __builtin_amdgcn_s_barrier();  // step i's tile visible to all waves

        const ushortT* tA = &sA[buf][0];
        const ushortT* tB = &sB[buf][0];
        __builtin_amdgcn_s_setprio(1);
#pragma unroll
        for (int kk = 0; kk < 2; ++kk) {
            int c = kk * 2 + hsel;
            half8 a0 = ldfrag32(tA, ra0, c);
            half8 a1 = ldfrag32(tA, ra1, c);
            half8 b0 = ldfrag32(tB, rb0, c);
            half8 b1 = ldfrag32(tB, rb1, c);
            acc[0][0] = __builtin_amdgcn_mfma_f32_32x32x16_f16(a0, b0, acc[0][0], 0, 0, 0);
            acc[0][1] = __builtin_amdgcn_mfma_f32_32x32x16_f16(a0, b1, acc[0][1], 0, 0, 0);
            acc[1][0] = __builtin_amdgcn_mfma_f32_32x32x16_f16(a1, b0, acc[1][0], 0, 0, 0);
            acc[1][1] = __builtin_amdgcn_mfma_f32_32x32x16_f16(a1, b1, acc[1][1], 0, 0, 0);
        }
        __builtin_amdgcn_s_setprio(0);
        asm volatile("" ::: "memory"); // keep ds_reads above the barrier
        __builtin_amdgcn_s_barrier();  // all reads of buf done before re-stage
    }
#undef STAGE

    // Store i16 partial: round(-2*acc*16).
    short* pk = pws + (size_t)kh * PLANE;
#pragma unroll
    for (int i = 0; i < 2; ++i)
#pragma unroll
        for (int j = 0; j < 2; ++j) {
            const int gcol = col0 + wc + j * 32 + m0;
#pragma unroll
            for (int r = 0; r < 16; ++r) {
                int ri = (r & 3) + 8 * (r >> 2) + 4 * hsel;
                int grow = row0 + wr + i * 32 + ri;
                float q = fmaxf(fminf(acc[i][j][r] * (-2.0f * PSCALE),
                                      32767.f), -32767.f);
                pk[(size_t)grow * N_CLUST + gcol] = (short)__float2int_rn(q);
            }
        }
}

// ---------------- rescreen: exact argmin per row + winner scatter ---------
// Vectorized (v6). One wave per row; lane l owns cols [l*16, l*16+16).
// Loads: 4 planes x 2 short8 (16B) + 4 float4 mm. Per-lane (min1, argmin,
// min2), 6-step shfl_xor merge (disjoint col sets -> exact). Fast path:
// min2-min1 > MARGIN. Rare exact path: fp64 dots, lowest-j tiebreak.
__global__ __launch_bounds__(256) void rescreen(
    const short* __restrict__ pws, const float* __restrict__ ysrc,
    const float* __restrict__ msrc, const float* __restrict__ yy,
    const float* __restrict__ mm, int* __restrict__ winner) {
    const int row = blockIdx.x * 4 + (threadIdx.x >> 6);
    const int l = threadIdx.x & 63;
    const size_t rb = (size_t)row * N_CLUST;

    // gather 16-col strip summed over 4 planes
    int sacc[16];
#pragma unroll
    for (int q = 0; q < 16; ++q) sacc[q] = 0;
    const short* base = pws + rb + l * 16;
#pragma unroll
    for (int pl = 0; pl < 4; ++pl) {
        const short8v* sp = (const short8v*)(base + pl * PLANE);
        short8v x0 = sp[0], x1 = sp[1];
#pragma unroll
        for (int e = 0; e < 8; ++e) {
            sacc[e] += (int)x0[e];
            sacc[8 + e] += (int)x1[e];
        }
    }
    float v[16];
    const float4* mmv = (const float4*)(mm + l * 16);
#pragma unroll
    for (int h = 0; h < 4; ++h) {
        float4 mv = mmv[h];
        v[h * 4 + 0] = mv.x + (float)sacc[h * 4 + 0] * (1.0f / PSCALE);
        v[h * 4 + 1] = mv.y + (float)sacc[h * 4 + 1] * (1.0f / PSCALE);
        v[h * 4 + 2] = mv.z + (float)sacc[h * 4 + 2] * (1.0f / PSCALE);
        v[h * 4 + 3] = mv.w + (float)sacc[h * 4 + 3] * (1.0f / PSCALE);
    }

    // per-lane min1/argmin/min2 (ascending q: strict < keeps lowest col)
    float m1 = v[0], m2 = 3.0e38f;
    int a1 = l * 16;
#pragma unroll
    for (int q = 1; q < 16; ++q) {
        float x = v[q];
        if (x < m1) { m2 = m1; m1 = x; a1 = l * 16 + q; }
        else m2 = fminf(m2, x);
    }
    // cross-lane merge (disjoint col sets)
#pragma unroll
    for (int s = 1; s <= 32; s <<= 1) {
        float o1 = __shfl_xor(m1, s, 64);
        int ob = __shfl_xor(a1, s, 64);
        float o2 = __shfl_xor(m2, s, 64);
        if (o1 < m1 || (o1 == m1 && ob < a1)) {
            m2 = fminf(o2, m1); m1 = o1; a1 = ob;
        } else {
            m2 = fminf(m2, o1);
        }
    }

    int zj;
    if (m2 - m1 > MARGIN) {
        zj = a1;                      // unique screen winner
    } else {
        const float thr = m1 + MARGIN;
        double bestd = 1e300;
        int bestj = 0x7FFFFFFF;
        const float yyr = yy[row];
        const float4* yp = (const float4*)(ysrc + (size_t)row * KDIM);
        for (int q = 0; q < 16; ++q) {
            unsigned long long mask = __ballot(v[q] <= thr);
            while (mask) {
                int lb = __ffsll((unsigned long long)mask) - 1;
                mask &= mask - 1;
                int j = lb * 16 + q;
                const float4* mp = (const float4*)(msrc + (size_t)j * KDIM);
                double acc = 0.0;
#pragma unroll
                for (int tt = 0; tt < 16; ++tt) {
                    float4 a = yp[l + 64 * tt];
                    float4 b = mp[l + 64 * tt];
                    acc += (double)a.x * b.x + (double)a.y * b.y +
                           (double)a.z * b.z + (double)a.w * b.w;
                }
#pragma unroll
                for (int s = 1; s <= 32; s <<= 1)
                    acc += __shfl_xor(acc, s, 64);
                double d2x = (double)yyr - 2.0 * acc + (double)mm[j];
                if (d2x < bestd || (d2x == bestd && j < bestj)) {
                    bestd = d2x; bestj = j;   // lowest j wins ties
                }
            }
        }
        zj = bestj;
    }
    if (l == 0) atomicMax(&winner[zj], row);   // fused pick_winner
}

// ---------------- output ----------------
__global__ __launch_bounds__(256) void write_out(
    const float* __restrict__ y, const float* __restrict__ m,
    const float* __restrict__ sd, const int* __restrict__ winner,
    float* __restrict__ out) {
    const int idx = blockIdx.x;
    const int t = threadIdx.x;
    const int w = winner[idx];
    const float4* mp = (const float4*)(m + (size_t)idx * KDIM);
    const float4* sp = (const float4*)(sd + (size_t)idx * KDIM);
    float4* om = (float4*)(out + (size_t)idx * KDIM);
    float4* os = (float4*)(out + (size_t)(N_CLUST + idx) * KDIM);
    if (w >= 0) {
        const float4* yp = (const float4*)(y + (size_t)w * KDIM);
        for (int i = t; i < KDIM / 4; i += 256) {
            float4 mv = mp[i], yv = yp[i], sv = sp[i];
            float4 nm, ns;
            nm.x = mv.x * EMA_OLD + yv.x * EMA_NEW;
            nm.y = mv.y * EMA_OLD + yv.y * EMA_NEW;
            nm.z = mv.z * EMA_OLD + yv.z * EMA_NEW;
            nm.w = mv.w * EMA_OLD + yv.w * EMA_NEW;
            float dx = nm.x - yv.x, dy = nm.y - yv.y;
            float dz = nm.z - yv.z, dw = nm.w - yv.w;
            ns.x = dx * dx * EMA_OLD + sv.x * EMA_NEW;
            ns.y = dy * dy * EMA_OLD + sv.y * EMA_NEW;
            ns.z = dz * dz * EMA_OLD + sv.z * EMA_NEW;
            ns.w = dw * dw * EMA_OLD + sv.w * EMA_NEW;
            om[i] = nm;
            os[i] = ns;
        }
    } else {
        for (int i = t; i < KDIM / 4; i += 256) {
            om[i] = mp[i];
            os[i] = sp[i];
        }
    }
}

extern "C" void kernel_launch(void* const* d_in, const int* in_sizes, int n_in,
                              void* d_out, int out_size, void* d_ws,
                              size_t ws_size, hipStream_t stream) {
    const float* y  = (const float*)d_in[0];
    const float* m  = (const float*)d_in[1];
    const float* sd = (const float*)d_in[2];
    float* out = (float*)d_out;

    char* ws = (char*)d_ws;
    int* winner = (int*)(ws + WS_WINNER_OFF);
    float* yy   = (float*)(ws + WS_YY_OFF);
    float* mm   = (float*)(ws + WS_MM_OFF);
    short* pws  = (short*)(ws + WS_P_OFF);
    ushortT* yhi = (ushortT*)(ws + WS_YHI_OFF);
    ushortT* mhi = (ushortT*)(ws + WS_MHI_OFF);

    convert_sumsq<<<B_ROWS + N_CLUST, 256, 0, stream>>>(
        y, m, yhi, mhi, yy, mm, winner);

    screen_gemm<<<(B_ROWS / 128) * (N_CLUST / 128) * 4, 256, 0, stream>>>(
        yhi, mhi, pws);

    rescreen<<<B_ROWS / 4, 256, 0, stream>>>(pws, y, m, yy, mm, winner);

    write_out<<<N_CLUST, 256, 0, stream>>>(y, m, sd, winner, out);
}

// Round 8
// 216.762 us; speedup vs baseline: 1.0088x; 1.0088x over previous
//
#include <hip/hip_runtime.h>

#define B_ROWS 4096
#define N_CLUST 1024
#define KDIM 4096
#define NKT 32          // source k-tiles of 128 halfs
#define NSTEP 16        // BK=64 steps per block (split-K x4: 8 kt x 2)

#define EMA_OLD 0.01f
#define EMA_NEW 0.99f
#define MARGIN 2.0f     // screen error: ~0.27 f16 + 0.125 i16 quant << 2.0
#define PSCALE 16.0f    // i16 partial quantization scale
#define PLANE ((size_t)B_ROWS * N_CLUST)

typedef unsigned short ushortT;
typedef _Float16 half8 __attribute__((ext_vector_type(8)));
typedef short short8v __attribute__((ext_vector_type(8)));
typedef float f32x16 __attribute__((ext_vector_type(16)));

// ---------------- workspace layout (bytes) ----------------
#define WS_WINNER_OFF 0                  // i32[1024], init by convert_sumsq
#define WS_YY_OFF     20480              // f32[4096]
#define WS_MM_OFF     36864              // f32[1024]
#define WS_P_OFF      65536              // i16[4][4096][1024] = 4 x 8 MiB
#define WS_YHI_OFF    (WS_P_OFF + 33554432)      // 33.6 MB
#define WS_MHI_OFF    (WS_YHI_OFF + 33554432)    // 8.4 MB
#define WS_END        (WS_MHI_OFF + 8388608)     // ~75 MB

// ---------------- fused f16-hi convert + row sum-of-squares ----------------
// Tiled layout: block (rb, kt) of 64 rows x 128 halfs contiguous (16 KB).
// Within a row (16 chunks of 16B), logical chunk c stored at p = c ^ (r&15).
// m-branch blocks also init winner[row] = -1 (replaces the memset node).
__global__ __launch_bounds__(256) void convert_sumsq(
    const float* __restrict__ ysrc, const float* __restrict__ msrc,
    ushortT* __restrict__ yhi, ushortT* __restrict__ mhi,
    float* __restrict__ yy, float* __restrict__ mm,
    int* __restrict__ winner) {
    const int blk = blockIdx.x;
    const float* src;
    ushortT* hi;
    float* out;
    int row;
    if (blk < B_ROWS) {
        src = ysrc; hi = yhi; out = yy + blk; row = blk;
    } else {
        row = blk - B_ROWS;
        src = msrc; hi = mhi; out = mm + row;
        if (threadIdx.x == 0) winner[row] = -1;   // fused memset
    }
    const int r = row & 63, rb = row >> 6;
    const int t = threadIdx.x;
    float s = 0.f;
#pragma unroll
    for (int h = 0; h < 2; ++h) {
        int ci = h * 256 + t;        // physical chunk in row [0,512)
        int kt = ci >> 4, p = ci & 15;
        int c = p ^ (r & 15);
        const float* sp = src + ((size_t)row << 12) + kt * 128 + c * 8;
        float4 v0 = *(const float4*)sp;
        float4 v1 = *(const float4*)(sp + 4);
        float vv[8] = {v0.x, v0.y, v0.z, v0.w, v1.x, v1.y, v1.z, v1.w};
        half8 hv;
#pragma unroll
        for (int i = 0; i < 8; ++i) {
            hv[i] = (_Float16)vv[i];
            s += vv[i] * vv[i];
        }
        size_t off = (((size_t)rb * NKT + kt) * 64 + r) * 128 + p * 8;
        *(half8*)(hi + off) = hv;
    }
    for (int off = 32; off > 0; off >>= 1) s += __shfl_down(s, off, 64);
    __shared__ float red[4];
    if ((t & 63) == 0) red[t >> 6] = s;
    __syncthreads();
    if (t == 0) out[0] = red[0] + red[1] + red[2] + red[3];
}

// ---------------- screen GEMM: partials of -2*Yhi@Mhi^T ------------------
__device__ __forceinline__ void gload_lds16(const void* g, void* l) {
    __builtin_amdgcn_global_load_lds(
        (const __attribute__((address_space(1))) unsigned int*)g,
        (__attribute__((address_space(3))) unsigned int*)l, 16, 0, 0);
}

// Pair-interleaved LDS layout (BK=64, conflict-free — v5, measured 0):
// phys_byte(r, c) = (r>>1)*256 + ((((r&1)<<3)|c) ^ ((r>>1)&15))*16.
// Among 32 lanes exactly 2 share a 16B slot -> 2-way = free.
__device__ __forceinline__ half8 ldfrag_pair(const ushortT* s, int r, int c) {
    int q = r >> 1;
    int sl = ((((r & 1) << 3) | c) ^ (q & 15));
    return *(const half8*)(s + q * 128 + sl * 8);
}

// v9 GEMM = v5's proven structure (48.4 us, best of 5 structures tested:
// v1 2KB/MFMA=60.7, v3 2blk=50.0, v4 conflicts=54.6, v7 dbuf-2blk=50.7,
// v8 BK32=58.5). 128x128 block tile, 4 waves each 64x64, BK=64 single-
// buffered 32 KB -> 4 blocks/CU. Split-K x4, i16 partials at scale 16.
// DIAGNOSTIC SPLIT (this round): launched as TWO 512-block dispatches
// (bx_base 0 and 16) so each half ~25-27 us -> drops the rocprof top-5
// cutoff below the aux kernels, un-blinding the stable ~163 us non-GEMM
// block (aux kernels vs harness-fixed overhead). Costs ~2-4 us.
__global__ __launch_bounds__(256, 4) void screen_gemm(
    const ushortT* __restrict__ Ah, const ushortT* __restrict__ Bh,
    short* __restrict__ pws, int bx_base) {
    __shared__ __align__(16) ushortT sA[128 * 64];   // 16 KB
    __shared__ __align__(16) ushortT sB[128 * 64];   // 16 KB

    const int t = threadIdx.x, w = t >> 6, l = t & 63;
    const int by = blockIdx.x & 7;            // col panel -> XCD pinned
    const int kh = (blockIdx.x >> 3) & 3;     // K quarter
    const int bx = bx_base + (blockIdx.x >> 5);   // row tile 0..31
    const int row0 = bx * 128, col0 = by * 128;
    const int wr = (w >> 1) * 64, wc = (w & 1) * 64;   // wave 64x64 tile
    const int m0 = l & 31, hsel = l >> 5;

    // Per-lane source offsets for the 4 staged chunks (ks flips byte bit 7).
    int laneoff[4];
#pragma unroll
    for (int j = 0; j < 4; ++j) {
        int g = w * 4 + j;
        int q = g * 4 + (l >> 4);
        int u = (l & 15) ^ (q & 15);
        int rr = 2 * q + (u >> 3);
        int R = rr & 63;
        int hi3 = (R >> 3) & 1;
        laneoff[j] = R * 256 + ((((hi3 << 3) | ((u & 7) ^ (R & 7)))) << 4);
    }

    f32x16 acc[2][2];
#pragma unroll
    for (int i = 0; i < 2; ++i)
#pragma unroll
        for (int j = 0; j < 2; ++j)
#pragma unroll
            for (int r = 0; r < 16; ++r) acc[i][j][r] = 0.f;

    const int ra0 = wr + m0, ra1 = wr + 32 + m0;
    const int rb0 = wc + m0, rb1 = wc + 32 + m0;

#pragma unroll 2
    for (int i = 0; i < NSTEP; ++i) {
        const int kt_ = kh * (NKT / 4) + (i >> 1);
        const int ks_ = i & 1;
        __syncthreads();   // all waves done reading LDS from previous step
#pragma unroll
        for (int j = 0; j < 4; ++j) {
            const int g = w * 4 + j;
            const int lo = laneoff[j] ^ (ks_ << 7);
            const size_t tbA = ((size_t)((2 * bx + (g >> 3)) * NKT + kt_) << 14);
            const size_t tbB = ((size_t)((2 * by + (g >> 3)) * NKT + kt_) << 14);
            gload_lds16((const char*)Ah + tbA + lo, (char*)sA + g * 1024);
            gload_lds16((const char*)Bh + tbB + lo, (char*)sB + g * 1024);
        }
        __syncthreads();   // implicit vmcnt(0): staged tile visible

#pragma unroll
        for (int kk = 0; kk < 4; ++kk) {
            int c = kk * 2 + hsel;
            half8 a0 = ldfrag_pair(sA, ra0, c);
            half8 a1 = ldfrag_pair(sA, ra1, c);
            half8 b0 = ldfrag_pair(sB, rb0, c);
            half8 b1 = ldfrag_pair(sB, rb1, c);
            acc[0][0] = __builtin_amdgcn_mfma_f32_32x32x16_f16(a0, b0, acc[0][0], 0, 0, 0);
            acc[0][1] = __builtin_amdgcn_mfma_f32_32x32x16_f16(a0, b1, acc[0][1], 0, 0, 0);
            acc[1][0] = __builtin_amdgcn_mfma_f32_32x32x16_f16(a1, b0, acc[1][0], 0, 0, 0);
            acc[1][1] = __builtin_amdgcn_mfma_f32_32x32x16_f16(a1, b1, acc[1][1], 0, 0, 0);
        }
    }

    // Store i16 partial: round(-2*acc*16). |2 acc| <= ~16 sigma = 1024 << 2047.
    short* pk = pws + (size_t)kh * PLANE;
#pragma unroll
    for (int i = 0; i < 2; ++i)
#pragma unroll
        for (int j = 0; j < 2; ++j) {
            const int gcol = col0 + wc + j * 32 + m0;
#pragma unroll
            for (int r = 0; r < 16; ++r) {
                int ri = (r & 3) + 8 * (r >> 2) + 4 * hsel;
                int grow = row0 + wr + i * 32 + ri;
                float q = fmaxf(fminf(acc[i][j][r] * (-2.0f * PSCALE),
                                      32767.f), -32767.f);
                pk[(size_t)grow * N_CLUST + gcol] = (short)__float2int_rn(q);
            }
        }
}

// ---------------- rescreen: exact argmin per row + winner scatter ---------
// Vectorized (v6). One wave per row; lane l owns cols [l*16, l*16+16).
// Loads: 4 planes x 2 short8 (16B) + 4 float4 mm. Per-lane (min1, argmin,
// min2), 6-step shfl_xor merge (disjoint col sets -> exact). Fast path:
// min2-min1 > MARGIN. Rare exact path: fp64 dots, lowest-j tiebreak.
__global__ __launch_bounds__(256) void rescreen(
    const short* __restrict__ pws, const float* __restrict__ ysrc,
    const float* __restrict__ msrc, const float* __restrict__ yy,
    const float* __restrict__ mm, int* __restrict__ winner) {
    const int row = blockIdx.x * 4 + (threadIdx.x >> 6);
    const int l = threadIdx.x & 63;
    const size_t rb = (size_t)row * N_CLUST;

    // gather 16-col strip summed over 4 planes
    int sacc[16];
#pragma unroll
    for (int q = 0; q < 16; ++q) sacc[q] = 0;
    const short* base = pws + rb + l * 16;
#pragma unroll
    for (int pl = 0; pl < 4; ++pl) {
        const short8v* sp = (const short8v*)(base + pl * PLANE);
        short8v x0 = sp[0], x1 = sp[1];
#pragma unroll
        for (int e = 0; e < 8; ++e) {
            sacc[e] += (int)x0[e];
            sacc[8 + e] += (int)x1[e];
        }
    }
    float v[16];
    const float4* mmv = (const float4*)(mm + l * 16);
#pragma unroll
    for (int h = 0; h < 4; ++h) {
        float4 mv = mmv[h];
        v[h * 4 + 0] = mv.x + (float)sacc[h * 4 + 0] * (1.0f / PSCALE);
        v[h * 4 + 1] = mv.y + (float)sacc[h * 4 + 1] * (1.0f / PSCALE);
        v[h * 4 + 2] = mv.z + (float)sacc[h * 4 + 2] * (1.0f / PSCALE);
        v[h * 4 + 3] = mv.w + (float)sacc[h * 4 + 3] * (1.0f / PSCALE);
    }

    // per-lane min1/argmin/min2 (ascending q: strict < keeps lowest col)
    float m1 = v[0], m2 = 3.0e38f;
    int a1 = l * 16;
#pragma unroll
    for (int q = 1; q < 16; ++q) {
        float x = v[q];
        if (x < m1) { m2 = m1; m1 = x; a1 = l * 16 + q; }
        else m2 = fminf(m2, x);
    }
    // cross-lane merge (disjoint col sets)
#pragma unroll
    for (int s = 1; s <= 32; s <<= 1) {
        float o1 = __shfl_xor(m1, s, 64);
        int ob = __shfl_xor(a1, s, 64);
        float o2 = __shfl_xor(m2, s, 64);
        if (o1 < m1 || (o1 == m1 && ob < a1)) {
            m2 = fminf(o2, m1); m1 = o1; a1 = ob;
        } else {
            m2 = fminf(m2, o1);
        }
    }

    int zj;
    if (m2 - m1 > MARGIN) {
        zj = a1;                      // unique screen winner
    } else {
        const float thr = m1 + MARGIN;
        double bestd = 1e300;
        int bestj = 0x7FFFFFFF;
        const float yyr = yy[row];
        const float4* yp = (const float4*)(ysrc + (size_t)row * KDIM);
        for (int q = 0; q < 16; ++q) {
            unsigned long long mask = __ballot(v[q] <= thr);
            while (mask) {
                int lb = __ffsll((unsigned long long)mask) - 1;
                mask &= mask - 1;
                int j = lb * 16 + q;
                const float4* mp = (const float4*)(msrc + (size_t)j * KDIM);
                double acc = 0.0;
#pragma unroll
                for (int tt = 0; tt < 16; ++tt) {
                    float4 a = yp[l + 64 * tt];
                    float4 b = mp[l + 64 * tt];
                    acc += (double)a.x * b.x + (double)a.y * b.y +
                           (double)a.z * b.z + (double)a.w * b.w;
                }
#pragma unroll
                for (int s = 1; s <= 32; s <<= 1)
                    acc += __shfl_xor(acc, s, 64);
                double d2x = (double)yyr - 2.0 * acc + (double)mm[j];
                if (d2x < bestd || (d2x == bestd && j < bestj)) {
                    bestd = d2x; bestj = j;   // lowest j wins ties
                }
            }
        }
        zj = bestj;
    }
    if (l == 0) atomicMax(&winner[zj], row);   // fused pick_winner
}

// ---------------- output ----------------
__global__ __launch_bounds__(256) void write_out(
    const float* __restrict__ y, const float* __restrict__ m,
    const float* __restrict__ sd, const int* __restrict__ winner,
    float* __restrict__ out) {
    const int idx = blockIdx.x;
    const int t = threadIdx.x;
    const int w = winner[idx];
    const float4* mp = (const float4*)(m + (size_t)idx * KDIM);
    const float4* sp = (const float4*)(sd + (size_t)idx * KDIM);
    float4* om = (float4*)(out + (size_t)idx * KDIM);
    float4* os = (float4*)(out + (size_t)(N_CLUST + idx) * KDIM);
    if (w >= 0) {
        const float4* yp = (const float4*)(y + (size_t)w * KDIM);
        for (int i = t; i < KDIM / 4; i += 256) {
            float4 mv = mp[i], yv = yp[i], sv = sp[i];
            float4 nm, ns;
            nm.x = mv.x * EMA_OLD + yv.x * EMA_NEW;
            nm.y = mv.y * EMA_OLD + yv.y * EMA_NEW;
            nm.z = mv.z * EMA_OLD + yv.z * EMA_NEW;
            nm.w = mv.w * EMA_OLD + yv.w * EMA_NEW;
            float dx = nm.x - yv.x, dy = nm.y - yv.y;
            float dz = nm.z - yv.z, dw = nm.w - yv.w;
            ns.x = dx * dx * EMA_OLD + sv.x * EMA_NEW;
            ns.y = dy * dy * EMA_OLD + sv.y * EMA_NEW;
            ns.z = dz * dz * EMA_OLD + sv.z * EMA_NEW;
            ns.w = dw * dw * EMA_OLD + sv.w * EMA_NEW;
            om[i] = nm;
            os[i] = ns;
        }
    } else {
        for (int i = t; i < KDIM / 4; i += 256) {
            om[i] = mp[i];
            os[i] = sp[i];
        }
    }
}

extern "C" void kernel_launch(void* const* d_in, const int* in_sizes, int n_in,
                              void* d_out, int out_size, void* d_ws,
                              size_t ws_size, hipStream_t stream) {
    const float* y  = (const float*)d_in[0];
    const float* m  = (const float*)d_in[1];
    const float* sd = (const float*)d_in[2];
    float* out = (float*)d_out;

    char* ws = (char*)d_ws;
    int* winner = (int*)(ws + WS_WINNER_OFF);
    float* yy   = (float*)(ws + WS_YY_OFF);
    float* mm   = (float*)(ws + WS_MM_OFF);
    short* pws  = (short*)(ws + WS_P_OFF);
    ushortT* yhi = (ushortT*)(ws + WS_YHI_OFF);
    ushortT* mhi = (ushortT*)(ws + WS_MHI_OFF);

    convert_sumsq<<<B_ROWS + N_CLUST, 256, 0, stream>>>(
        y, m, yhi, mhi, yy, mm, winner);

    // Diagnostic split: two 512-block halves (bx 0-15, 16-31) so each
    // dispatch ~25-27 us -> aux kernels >=26 us become visible in top-5.
    screen_gemm<<<512, 256, 0, stream>>>(yhi, mhi, pws, 0);
    screen_gemm<<<512, 256, 0, stream>>>(yhi, mhi, pws, 16);

    rescreen<<<B_ROWS / 4, 256, 0, stream>>>(pws, y, m, yy, mm, winner);

    write_out<<<N_CLUST, 256, 0, stream>>>(y, m, sd, winner, out);
}